// Round 1
// baseline (327.721 us; speedup 1.0000x reference)
//
#include <hip/hip_runtime.h>
#include <hip/hip_bf16.h>

// MaskedAttentionLayer: B=4, N=4096, D=256, fp32 in/out.
// Quirks honored: mask keeps strictly-future (m>n); softmax over the QUERY
// axis (per-column normalization). O = E @ (V/colsum) with E = exp(S), no
// max-subtraction needed (scores bounded); column m=0 fully masked ->
// uniform 1/4096 handled as epilogue constant V[b,0,:]/4096.

typedef float f32x4 __attribute__((ext_vector_type(4)));
typedef __bf16 bf16x8 __attribute__((ext_vector_type(8)));
typedef __bf16 bf16x4 __attribute__((ext_vector_type(4)));

#define MFMA16(a, b, c) __builtin_amdgcn_mfma_f32_16x16x32_bf16((a), (b), (c), 0, 0, 0)

constexpr int SEQ = 4096;
constexpr int DIM = 256;

// ---------------------------------------------------------------- k_prep
// Convert Wq/Wk/Wv to bf16, zero colsum. 768 blocks x 256.
__global__ void k_prep(const float* __restrict__ Wq, const float* __restrict__ Wk,
                       const float* __restrict__ Wv, __bf16* __restrict__ Wb,
                       float* __restrict__ colsum) {
  int i = blockIdx.x * 256 + threadIdx.x;
  if (i < 3 * 65536) {
    const float* src = (i < 65536) ? Wq : (i < 131072 ? Wk : Wv);
    Wb[i] = (__bf16)src[i & 65535];
  }
  if (i < 4 * SEQ) colsum[i] = 0.f;
}

// ---------------------------------------------------------------- k_qkv
// C[i,j] = sum_d x[i,d] * W[j,d]   (i over B*N=16384, j over 256)
// grid (128 i-tiles, 4 j-tiles, 3 weights), 256 threads (4 waves).
// Block tile 128x64, wave tile 64x32 (4x2 MFMA tiles).
__global__ __launch_bounds__(256, 1) void k_qkv(const float* __restrict__ x,
                                                const __bf16* __restrict__ Wb,
                                                __bf16* __restrict__ Qb,
                                                __bf16* __restrict__ Kb,
                                                __bf16* __restrict__ Vb) {
  __shared__ __bf16 xs[128][40];   // 32 k + 8 pad (80B stride, 2-way max)
  __shared__ __bf16 wsh[64][40];
  const int t = threadIdx.x, lane = t & 63, w = t >> 6;
  const int wi = w >> 1, wj = w & 1;
  const int ln = lane & 15, quad = lane >> 4, q8 = quad * 8;
  const int i0 = blockIdx.x * 128;
  const int j0 = blockIdx.y * 64;
  const __bf16* W = Wb + blockIdx.z * 65536;
  __bf16* Out = (blockIdx.z == 0) ? Qb : (blockIdx.z == 1 ? Kb : Vb);
  f32x4 acc[4][2] = {};
  for (int dk = 0; dk < 8; ++dk) {
    __syncthreads();
#pragma unroll
    for (int v = 0; v < 4; ++v) {
      int f = t + v * 256;             // 0..1023 float4 chunks
      int row = f >> 3, c4 = f & 7;    // 8 float4 per 32-wide row
      float4 val = *(const float4*)&x[(size_t)(i0 + row) * DIM + dk * 32 + c4 * 4];
      bf16x4 bv = {(__bf16)val.x, (__bf16)val.y, (__bf16)val.z, (__bf16)val.w};
      *(bf16x4*)&xs[row][c4 * 4] = bv;
    }
    {
      int row = t >> 2, c = t & 3;
      *(bf16x8*)&wsh[row][c * 8] =
          *(const bf16x8*)&W[(size_t)(j0 + row) * DIM + dk * 32 + c * 8];
    }
    __syncthreads();
    bf16x8 bb[2];
#pragma unroll
    for (int tj = 0; tj < 2; ++tj)
      bb[tj] = *(bf16x8*)&wsh[wj * 32 + tj * 16 + ln][q8];
#pragma unroll
    for (int ti = 0; ti < 4; ++ti) {
      bf16x8 a = *(bf16x8*)&xs[wi * 64 + ti * 16 + ln][q8];
#pragma unroll
      for (int tj = 0; tj < 2; ++tj)
        acc[ti][tj] = MFMA16(a, bb[tj], acc[ti][tj]);
    }
  }
#pragma unroll
  for (int ti = 0; ti < 4; ++ti)
#pragma unroll
    for (int tj = 0; tj < 2; ++tj)
#pragma unroll
      for (int r = 0; r < 4; ++r) {
        int row = i0 + wi * 64 + ti * 16 + quad * 4 + r;
        int col = j0 + wj * 32 + tj * 16 + ln;
        Out[(size_t)row * DIM + col] = (__bf16)acc[ti][tj][r];
      }
}

// ---------------------------------------------------------------- k_colsum
// colsum[b,m] = sum_{n<m} exp(q_n . k_m / 16).
// grid (32 m-tiles, 8 n-chunks, 4 b), 256 threads. Streams n in 64-row
// steps, d in 128-halves. Partial sums -> device-scope atomicAdd.
__global__ __launch_bounds__(256, 1) void k_colsum(const __bf16* __restrict__ Qb,
                                                   const __bf16* __restrict__ Kb,
                                                   float* __restrict__ colsum) {
  __shared__ __bf16 ksh[128][136];
  __shared__ __bf16 qs[64][136];
  const int t = threadIdx.x, lane = t & 63, w = t >> 6;
  const int ln = lane & 15, quad = lane >> 4, q8 = quad * 8;
  const int b = blockIdx.z;
  const int m0 = blockIdx.x * 128;
  const int nbase = blockIdx.y * 512;
  const __bf16* Qp = Qb + (size_t)b * SEQ * DIM;
  const __bf16* Kp = Kb + (size_t)b * SEQ * DIM;
  float partial[2] = {0.f, 0.f};
  for (int ns = 0; ns < 8; ++ns) {
    f32x4 acc[4][2] = {};
    for (int h = 0; h < 2; ++h) {
      __syncthreads();
      {
        int row = t >> 2, part = t & 3;
        const __bf16* src = &Qp[(size_t)(nbase + ns * 64 + row) * DIM + h * 128 + part * 32];
#pragma unroll
        for (int i = 0; i < 4; ++i)
          *(bf16x8*)&qs[row][part * 32 + i * 8] = *(const bf16x8*)&src[i * 8];
      }
      {
        int row = t >> 1, part = t & 1;
        const __bf16* src = &Kp[(size_t)(m0 + row) * DIM + h * 128 + part * 64];
#pragma unroll
        for (int i = 0; i < 8; ++i)
          *(bf16x8*)&ksh[row][part * 64 + i * 8] = *(const bf16x8*)&src[i * 8];
      }
      __syncthreads();
#pragma unroll
      for (int kf = 0; kf < 4; ++kf) {
        bf16x8 bb[2];
#pragma unroll
        for (int tm = 0; tm < 2; ++tm)
          bb[tm] = *(bf16x8*)&ksh[w * 32 + tm * 16 + ln][kf * 32 + q8];
#pragma unroll
        for (int tn = 0; tn < 4; ++tn) {
          bf16x8 a = *(bf16x8*)&qs[tn * 16 + ln][kf * 32 + q8];
#pragma unroll
          for (int tm = 0; tm < 2; ++tm)
            acc[tn][tm] = MFMA16(a, bb[tm], acc[tn][tm]);
        }
      }
    }
#pragma unroll
    for (int tn = 0; tn < 4; ++tn)
#pragma unroll
      for (int tm = 0; tm < 2; ++tm)
#pragma unroll
        for (int r = 0; r < 4; ++r) {
          int n_g = nbase + ns * 64 + tn * 16 + quad * 4 + r;
          int m_g = m0 + w * 32 + tm * 16 + ln;
          float e = (n_g < m_g) ? __expf(acc[tn][tm][r] * 0.0625f) : 0.f;
          partial[tm] += e;
        }
  }
#pragma unroll
  for (int tm = 0; tm < 2; ++tm) {
    float v = partial[tm];
    v += __shfl_xor(v, 16);
    v += __shfl_xor(v, 32);
    if (quad == 0)
      atomicAdd(&colsum[b * SEQ + m0 + w * 32 + tm * 16 + ln], v);
  }
}

// ---------------------------------------------------------------- k_vpt
// VpT[b][d][m] = V[b][m][d] / colsum[b][m]  (m==0 -> /4096, value unused by
// MFMA since E[:,0]==0, but must be finite). 64x64 LDS tile transpose.
__global__ void k_vpt(const __bf16* __restrict__ Vb, const float* __restrict__ colsum,
                      __bf16* __restrict__ VpT) {
  __shared__ __bf16 tile[64][72];
  const int t = threadIdx.x;
  const int b = blockIdx.z;
  const int m0 = blockIdx.x * 64, d0 = blockIdx.y * 64;
  {
    int row = t >> 2, part = t & 3;  // row = m-local
    float cs = colsum[b * SEQ + m0 + row];
    float inv = (m0 + row == 0) ? (1.0f / 4096.0f) : (1.0f / cs);
#pragma unroll
    for (int i = 0; i < 2; ++i) {
      int c = part * 2 + i;
      bf16x8 v = *(const bf16x8*)&Vb[(size_t)(b * SEQ + m0 + row) * DIM + d0 + c * 8];
      bf16x8 o;
#pragma unroll
      for (int j = 0; j < 8; ++j) o[j] = (__bf16)((float)v[j] * inv);
      *(bf16x8*)&tile[row][c * 8] = o;
    }
  }
  __syncthreads();
  {
    int row = t >> 2, part = t & 3;  // row = d-local
#pragma unroll
    for (int i = 0; i < 2; ++i) {
      int c = part * 2 + i;          // m chunk
      bf16x8 o;
#pragma unroll
      for (int j = 0; j < 8; ++j) o[j] = tile[c * 8 + j][row];
      *(bf16x8*)&VpT[(size_t)(b * DIM + d0 + row) * SEQ + m0 + c * 8] = o;
    }
  }
}

// ---------------------------------------------------------------- k_attn
// O[b, n0..n0+63, :] = sum_m E[n,m] * VpT[:,m]  + V[b,0,:]/4096.
// 256 blocks (1/CU), 512 threads (8 waves), 152 KiB LDS:
//   qs (Q tile, persistent) + ksh (K d-half) + ps (P tile, C->A layout
//   round-trip) + vs (VpT tile). Triangular skip: m-tiles < n0 are all-masked.
__global__ __launch_bounds__(512, 2) void k_attn(const __bf16* __restrict__ Qb,
                                                 const __bf16* __restrict__ Kb,
                                                 const __bf16* __restrict__ VpT,
                                                 const __bf16* __restrict__ Vb,
                                                 float* __restrict__ Out) {
  __shared__ __bf16 qs[64][264];    // 33792 B
  __shared__ __bf16 ksh[128][136];  // 34816 B
  __shared__ __bf16 ps[64][136];    // 17408 B
  __shared__ __bf16 vs[256][136];   // 69632 B   total 155648 B
  const int t = threadIdx.x, lane = t & 63, w = t >> 6;
  const int ln = lane & 15, quad = lane >> 4, q8 = quad * 8;
  // XCD-aware mapping: batch pinned to XCD pairs for K/VpT L2 locality.
  const int bid = blockIdx.x;            // 0..255
  const int b = (bid & 7) >> 1;
  const int nt = ((bid >> 3) << 1) | (bid & 1);  // 0..63
  const int n0 = nt * 64;
  const __bf16* Qp = Qb + (size_t)b * SEQ * DIM;
  const __bf16* Kp = Kb + (size_t)b * SEQ * DIM;
  const __bf16* Vt = VpT + (size_t)b * DIM * SEQ;
  const int wn = w & 1, wm = w >> 1;     // S: (n-half, m-quarter); PV: (n-half, d-quarter)
  // stage Q tile once
  {
    int row = t >> 3, part = t & 7;
    const __bf16* src = &Qp[(size_t)(n0 + row) * DIM + part * 32];
#pragma unroll
    for (int i = 0; i < 4; ++i)
      *(bf16x8*)&qs[row][part * 32 + i * 8] = *(const bf16x8*)&src[i * 8];
  }
  f32x4 accO[2][4] = {};  // [tn][td]
  for (int ms = (nt >> 1); ms < 32; ++ms) {
    __syncthreads();  // protect vs/ps/ksh from previous step's readers
    {                 // stage VpT tile: 256 d-rows x 128 m
      int row = t >> 1, part = t & 1;
      const __bf16* src = &Vt[(size_t)row * SEQ + ms * 128 + part * 64];
#pragma unroll
      for (int i = 0; i < 8; ++i)
        *(bf16x8*)&vs[row][part * 64 + i * 8] = *(const bf16x8*)&src[i * 8];
    }
    f32x4 accS[2][2] = {};
#pragma unroll
    for (int h = 0; h < 2; ++h) {
      if (h) __syncthreads();  // protect ksh overwrite
      {                        // stage K d-half: 128 m-rows x 128 d
        int row = t >> 2, part = t & 3;
        const __bf16* src = &Kp[(size_t)(ms * 128 + row) * DIM + h * 128 + part * 32];
#pragma unroll
        for (int i = 0; i < 4; ++i)
          *(bf16x8*)&ksh[row][part * 32 + i * 8] = *(const bf16x8*)&src[i * 8];
      }
      __syncthreads();
#pragma unroll
      for (int kf = 0; kf < 4; ++kf) {
        bf16x8 aa[2], bb[2];
#pragma unroll
        for (int tn = 0; tn < 2; ++tn)
          aa[tn] = *(bf16x8*)&qs[wn * 32 + tn * 16 + ln][h * 128 + kf * 32 + q8];
#pragma unroll
        for (int tm = 0; tm < 2; ++tm)
          bb[tm] = *(bf16x8*)&ksh[wm * 32 + tm * 16 + ln][kf * 32 + q8];
#pragma unroll
        for (int tn = 0; tn < 2; ++tn)
#pragma unroll
          for (int tm = 0; tm < 2; ++tm)
            accS[tn][tm] = MFMA16(aa[tn], bb[tm], accS[tn][tm]);
      }
    }
    // mask + exp, write P tile (C-layout regs -> [n][m] LDS for A-operand)
#pragma unroll
    for (int tn = 0; tn < 2; ++tn)
#pragma unroll
      for (int tm = 0; tm < 2; ++tm)
#pragma unroll
        for (int r = 0; r < 4; ++r) {
          int nl = wn * 32 + tn * 16 + quad * 4 + r;
          int ml = wm * 32 + tm * 16 + ln;
          int n_g = n0 + nl;
          int m_g = ms * 128 + ml;
          float e = (n_g >= m_g) ? 0.f : __expf(accS[tn][tm][r] * 0.0625f);
          ps[nl][ml] = (__bf16)e;
        }
    __syncthreads();
    // PV: O[n][d] += P[n][m] * VpT[d][m]
#pragma unroll
    for (int kf = 0; kf < 4; ++kf) {
      bf16x8 aa[2], bb[4];
#pragma unroll
      for (int tn = 0; tn < 2; ++tn)
        aa[tn] = *(bf16x8*)&ps[wn * 32 + tn * 16 + ln][kf * 32 + q8];
#pragma unroll
      for (int td = 0; td < 4; ++td)
        bb[td] = *(bf16x8*)&vs[wm * 64 + td * 16 + ln][kf * 32 + q8];
#pragma unroll
      for (int tn = 0; tn < 2; ++tn)
#pragma unroll
        for (int td = 0; td < 4; ++td)
          accO[tn][td] = MFMA16(aa[tn], bb[td], accO[tn][td]);
    }
  }
  // epilogue: + V[b,0,:]/4096 (the all-masked m=0 column), write fp32
  const __bf16* V0 = Vb + (size_t)b * SEQ * DIM;
  float* Op = Out + (size_t)b * SEQ * DIM;
#pragma unroll
  for (int tn = 0; tn < 2; ++tn)
#pragma unroll
    for (int td = 0; td < 4; ++td) {
      int col = wm * 64 + td * 16 + ln;
      float c0 = (float)V0[col] * (1.0f / 4096.0f);
#pragma unroll
      for (int r = 0; r < 4; ++r) {
        int row = n0 + wn * 32 + tn * 16 + quad * 4 + r;
        Op[(size_t)row * DIM + col] = accO[tn][td][r] + c0;
      }
    }
}

// ---------------------------------------------------------------- launch
extern "C" void kernel_launch(void* const* d_in, const int* in_sizes, int n_in,
                              void* d_out, int out_size, void* d_ws, size_t ws_size,
                              hipStream_t stream) {
  const float* x = (const float*)d_in[0];
  const float* Wq = (const float*)d_in[1];
  const float* Wk = (const float*)d_in[2];
  const float* Wv = (const float*)d_in[3];
  float* out = (float*)d_out;
  char* ws = (char*)d_ws;
  // ws layout (needs ~32.5 MB):
  __bf16* Qb = (__bf16*)(ws);                       // 8 MB
  __bf16* Kb = (__bf16*)(ws + (8u << 20));          // 8 MB
  __bf16* Vb = (__bf16*)(ws + (16u << 20));         // 8 MB
  __bf16* VpT = (__bf16*)(ws + (24u << 20));        // 8 MB
  float* colsum = (float*)(ws + (32u << 20));       // 64 KB
  __bf16* Wb = (__bf16*)(ws + (32u << 20) + (1u << 16));  // 384 KB

  k_prep<<<dim3(768), dim3(256), 0, stream>>>(Wq, Wk, Wv, Wb, colsum);
  k_qkv<<<dim3(128, 4, 3), dim3(256), 0, stream>>>(x, Wb, Qb, Kb, Vb);
  k_colsum<<<dim3(32, 8, 4), dim3(256), 0, stream>>>(Qb, Kb, colsum);
  k_vpt<<<dim3(64, 4, 4), dim3(256), 0, stream>>>(Vb, colsum, VpT);
  k_attn<<<dim3(256), dim3(512), 0, stream>>>(Qb, Kb, VpT, Vb, out);
}